// Round 8
// baseline (184.006 us; speedup 1.0000x reference)
//
#include <hip/hip_runtime.h>
#include <math.h>

#define EPS 1e-5f

typedef _Float16 half8 __attribute__((ext_vector_type(8)));
typedef float f32x4 __attribute__((ext_vector_type(4)));

// H/L global layout per row: [tile(8)][chunk(8)][col(64)] x 8 halves (16B units).

// bq in [0,96): b = bq/12, t = bq%12; x1seq row = b*12 + min(t+1, 11)
__device__ __forceinline__ int src_row(int bq) {
    int b = bq / 12, t = bq - b * 12;
    int t2 = (t + 1 < 12) ? (t + 1) : 11;
    return b * 12 + t2;
}

// ---------------- prep (768 blocks) + erase0 (96 blocks) fused ----------------
__global__ __launch_bounds__(256) void prep_kernel(
    const float* __restrict__ X,
    _Float16* __restrict__ H, _Float16* __restrict__ L, float* __restrict__ xn,
    const float* __restrict__ w0, const float* __restrict__ w1,
    _Float16* __restrict__ wh0, _Float16* __restrict__ wl0,
    _Float16* __restrict__ wh1, _Float16* __restrict__ wl1,
    const float* __restrict__ w_e, const float* __restrict__ b_e,
    const float* __restrict__ g_e, const float* __restrict__ be_e,
    const float* __restrict__ m_e, const float* __restrict__ v_e,
    float* __restrict__ bias0)
{
    __shared__ float lds[64 * 65];
    __shared__ float xnp[4 * 64];
    __shared__ float part[256];
    __shared__ float res[64];
    __shared__ float sy[64];
    int raw = blockIdx.x;
    int tid = threadIdx.x;
    if (raw >= 768) {
        int bq = raw - 768;
        int c = tid >> 2, p = tid & 3;
        const float* xb = X + (size_t)bq * 32768 + c * 512 + p * 128;
        float acc = 0.f;
        for (int ii = 0; ii < 128; ii += 4) {
            float4 v = *(const float4*)(xb + ii);
            acc += v.x + v.y + v.z + v.w;
        }
        part[tid] = acc;
        __syncthreads();
        if (p == 0) res[c] = (part[tid] + part[tid+1] + part[tid+2] + part[tid+3]) * (1.f/512.f);
        __syncthreads();
        if (tid < 64) {
            float a = b_e[tid];
            for (int cc = 0; cc < 64; ++cc) a += w_e[tid*64+cc] * res[cc];
            float s = g_e[tid] / sqrtf(v_e[tid] + EPS);
            sy[tid] = (a - m_e[tid]) * s + be_e[tid];
        }
        __syncthreads();
        if (tid < 64) {
            float a = 0.f;
            for (int cc = 0; cc < 64; ++cc) a += w0[tid * 128 + 64 + cc] * sy[cc];
            bias0[bq * 64 + tid] = a;
        }
        return;
    }
    int bq = raw % 96;
    int ct = raw / 96;
    const float* Xb = X + (size_t)bq * 32768 + ct * 64;
    for (int p = 0; p < 16; ++p) {
        int t = p * 256 + tid;
        int c = t >> 6, col = t & 63;
        lds[c * 65 + col] = Xb[c * 512 + col];
    }
    __syncthreads();
    int col = tid & 63, g = tid >> 6;
    half8 hv[2], lv[2];
    float s = 0.f;
    #pragma unroll
    for (int k = 0; k < 16; ++k) {
        int c = g * 16 + k;
        float v = lds[c * 65 + col];
        _Float16 h = (_Float16)v;
        _Float16 lo = (_Float16)(v - (float)h);
        hv[k >> 3][k & 7] = h;
        lv[k >> 3][k & 7] = lo;
        s += v * v;
    }
    size_t obase = (size_t)bq * 32768 + ((size_t)(ct * 8 + 2 * g) * 64 + col) * 8;
    *(half8*)(H + obase) = hv[0];
    *(half8*)(H + obase + 512) = hv[1];
    *(half8*)(L + obase) = lv[0];
    *(half8*)(L + obase + 512) = lv[1];
    xnp[g * 64 + col] = s;
    __syncthreads();
    if (tid < 64)
        xn[bq * 512 + ct * 64 + tid] =
            xnp[tid] + xnp[64 + tid] + xnp[128 + tid] + xnp[192 + tid];
    if (raw < 2) {
        const float* W = raw ? w1 : w0;
        _Float16* WH = raw ? wh1 : wh0;
        _Float16* WL = raw ? wl1 : wl0;
        for (int t = tid; t < 8192; t += 256) {
            int o = t >> 6, c = t & 63;
            float v = (o < 64) ? W[o * 128 + c]
                               : (W[(o - 64) * 128 + 64 + c] - W[(o - 64) * 128 + c]);
            _Float16 h = (_Float16)v;
            WH[t] = h;
            WL[t] = (_Float16)(v - (float)h);
        }
    }
}

// ---------------- kNN v15: barrier-free main loop, A-fragments from L2 ----
// Key layout: [key25 bits 31:7][(7-jt)<<4 | (15-slot) bits 6:0].
// Higher packed word = better score; ties resolve to lower j (matches top_k).
// Outputs bit-identical to R3/R7 (top-20 u16 idx + hi16 keys per query).
// No LDS tile staging: same-bq blocks land on one XCD (stride 96 = 0 mod 8),
// so j-tile reads are L2-hits; waves free-run with zero main-loop barriers.
__global__ __launch_bounds__(256, 4) void knn_kernel(
    const _Float16* __restrict__ H, const _Float16* __restrict__ L,
    const float* __restrict__ xn,
    unsigned short* __restrict__ idx_out, unsigned short* __restrict__ key_out)
{
    __shared__ unsigned MVb[5376];      // 21 KB final-merge scratch (4 waves x 1344)
    __shared__ float sxn[512];          // staged norms
    int raw = blockIdx.x;
    int bq = raw % 96;
    int itile = raw / 96;
    int tid = threadIdx.x, w = tid >> 6, l = tid & 63;
    int lane16 = l & 15, quad = l >> 4;
    const size_t base = (size_t)bq * 32768;
    const _Float16* Hb = H + base;
    const _Float16* Lb = L + base;

    int irow = itile * 64 + w * 16 + lane16;
    size_t bo = ((size_t)(itile * 8 + quad) * 64 + (w * 16 + lane16)) * 8;
    half8 Bh0 = *(const half8*)(Hb + bo);
    half8 Bh1 = *(const half8*)(Hb + bo + 2048);
    half8 Bl0 = *(const half8*)(Lb + bo);
    half8 Bl1 = *(const half8*)(Lb + bo + 2048);

    unsigned kv[20];
    #pragma unroll
    for (int qq = 0; qq < 20; ++qq) kv[qq] = 0u;

    auto casu = [](unsigned& a, unsigned& b) {
        unsigned mn = a < b ? a : b;
        unsigned mx = a < b ? b : a;
        a = mn; b = mx;
    };

    {   // stage xn row only
        const float* xnb = xn + bq * 512;
        sxn[tid] = xnb[tid]; sxn[256 + tid] = xnb[256 + tid];
    }
    __syncthreads();
    for (int jt = 0; jt < 8; ++jt) {
        const _Float16* jH = Hb + jt * 4096;
        const _Float16* jL = Lb + jt * 4096;
        unsigned scb = (unsigned)((7 - jt) << 4);      // scalar per jt
        unsigned d[16];
        #pragma unroll
        for (int g = 0; g < 4; ++g) {
            int u = quad * 64 + g * 16 + lane16;
            half8 Ah0 = *(const half8*)(jH + (size_t)u * 8);
            half8 Ah1 = *(const half8*)(jH + (size_t)u * 8 + 2048);
            half8 Al0 = *(const half8*)(jL + (size_t)u * 8);
            half8 Al1 = *(const half8*)(jL + (size_t)u * 8 + 2048);
            f32x4 acc = {0.f, 0.f, 0.f, 0.f};
            acc = __builtin_amdgcn_mfma_f32_16x16x32_f16(Ah0, Bh0, acc, 0, 0, 0);
            acc = __builtin_amdgcn_mfma_f32_16x16x32_f16(Ah1, Bh1, acc, 0, 0, 0);
            acc = __builtin_amdgcn_mfma_f32_16x16x32_f16(Al0, Bh0, acc, 0, 0, 0);
            acc = __builtin_amdgcn_mfma_f32_16x16x32_f16(Al1, Bh1, acc, 0, 0, 0);
            acc = __builtin_amdgcn_mfma_f32_16x16x32_f16(Ah0, Bl0, acc, 0, 0, 0);
            acc = __builtin_amdgcn_mfma_f32_16x16x32_f16(Ah1, Bl1, acc, 0, 0, 0);
            int jb = jt * 64 + g * 16 + quad * 4;
            float4 xn4 = *(const float4*)&sxn[jb];
            #pragma unroll
            for (int r = 0; r < 4; ++r) {
                float xnr = (r == 0 ? xn4.x : r == 1 ? xn4.y : r == 2 ? xn4.z : xn4.w);
                float sc = fmaf(2.f, acc[r], -xnr);
                int bi = __float_as_int(sc);
                unsigned u2 = (unsigned)(bi ^ ((bi >> 31) | 0x80000000));
                int slot = g * 4 + r;
                d[slot] = (u2 & 0xFFFFFF80u) | (scb | (unsigned)(15 - slot));
            }
        }
        // bitonic sort 16 ascending
        #pragma unroll
        for (int p = 1; p < 16; p <<= 1) {
            #pragma unroll
            for (int k = p; k >= 1; k >>= 1) {
                #pragma unroll
                for (int j = k & (p - 1); j + k < 16; j += 2 * k) {
                    #pragma unroll
                    for (int i = 0; i < k; ++i) {
                        if ((i + j + k < 16) &&
                            ((i + j) / (2 * p) == (i + j + k) / (2 * p)))
                            casu(d[i + j], d[i + j + k]);
                    }
                }
            }
        }
        // merge into asc top-20 list: elementwise max (valley), then bitonic cleanup
        #pragma unroll
        for (int i = 0; i < 16; ++i) {
            unsigned dv = d[15 - i];
            kv[i] = kv[i] > dv ? kv[i] : dv;
        }
        // valley(20) -> asc: merge-32 network with OOB (>=20, +inf pads) dropped
        casu(kv[0],kv[16]); casu(kv[1],kv[17]); casu(kv[2],kv[18]); casu(kv[3],kv[19]);
        casu(kv[0],kv[8]);  casu(kv[1],kv[9]);  casu(kv[2],kv[10]); casu(kv[3],kv[11]);
        casu(kv[4],kv[12]); casu(kv[5],kv[13]); casu(kv[6],kv[14]); casu(kv[7],kv[15]);
        casu(kv[0],kv[4]);  casu(kv[1],kv[5]);  casu(kv[2],kv[6]);  casu(kv[3],kv[7]);
        casu(kv[8],kv[12]); casu(kv[9],kv[13]); casu(kv[10],kv[14]); casu(kv[11],kv[15]);
        casu(kv[0],kv[2]);  casu(kv[1],kv[3]);  casu(kv[4],kv[6]);  casu(kv[5],kv[7]);
        casu(kv[8],kv[10]); casu(kv[9],kv[11]); casu(kv[12],kv[14]); casu(kv[13],kv[15]);
        casu(kv[16],kv[18]); casu(kv[17],kv[19]);
        casu(kv[0],kv[1]);  casu(kv[2],kv[3]);  casu(kv[4],kv[5]);  casu(kv[6],kv[7]);
        casu(kv[8],kv[9]);  casu(kv[10],kv[11]); casu(kv[12],kv[13]); casu(kv[14],kv[15]);
        casu(kv[16],kv[17]); casu(kv[18],kv[19]);
    }
    // dump per-lane lists into dedicated scratch (no aliasing -> no pre-barrier)
    #pragma unroll
    for (int qq = 0; qq < 20; ++qq)
        MVb[w * 1344 + (lane16 * 4 + quad) * 21 + qq] = kv[qq];
    __syncthreads();
    if (quad == 0) {
        // raw packed compare is the full (key, smaller-j) order:
        //  - within a quad, low 7 bits order by j already
        //  - across quads, equal packed words differ in j only by quad*4 -> first quad wins
        const unsigned* MV = MVb + w * 1344 + lane16 * 84;
        int p0 = 19, p1 = 19, p2 = 19, p3 = 19;
        unsigned v0 = MV[19], v1 = MV[21 + 19], v2 = MV[42 + 19], v3 = MV[63 + 19];
        unsigned short* op = idx_out + ((size_t)bq * 512 + irow) * 20;
        unsigned short* kp = key_out + ((size_t)bq * 512 + irow) * 20;
        for (int t = 0; t < 20; ++t) {
            int bc = 0; unsigned bv = v0;
            if (v1 > bv) { bv = v1; bc = 1; }
            if (v2 > bv) { bv = v2; bc = 2; }
            if (v3 > bv) { bv = v3; bc = 3; }
            int bits = (int)(bv & 127u), jtv = 7 - (bits >> 4), cod = 15 - (bits & 15);
            int j = jtv * 64 + ((cod >> 2) << 4) + bc * 4 + (cod & 3);
            op[t] = (unsigned short)j;
            kp[t] = (unsigned short)(bv >> 16);
            if (bc == 0)      { --p0; v0 = MV[p0 < 0 ? 0 : p0]; }
            else if (bc == 1) { --p1; v1 = MV[21 + (p1 < 0 ? 0 : p1)]; }
            else if (bc == 2) { --p2; v2 = MV[42 + (p2 < 0 ? 0 : p2)]; }
            else              { --p3; v3 = MV[63 + (p3 < 0 ? 0 : p3)]; }
        }
    }
}

// ---------------- derive v2 (96 blocks x 1024 threads): corre + erase1 + merge ----
// All list/merge state staged to LDS; shuffle reductions; 16 waves/block for latency hiding.
__global__ __launch_bounds__(1024) void derive_kernel(
    const float* __restrict__ x, const float* __restrict__ x0vec,
    const float* __restrict__ w_reduce,
    const unsigned short* __restrict__ idxA, const unsigned short* __restrict__ keyA,
    const float* __restrict__ xn,
    const float* __restrict__ w_e, const float* __restrict__ b_e,
    const float* __restrict__ g_e, const float* __restrict__ be_e,
    const float* __restrict__ m_e, const float* __restrict__ v_e,
    const float* __restrict__ w1,
    unsigned short* __restrict__ idxB, float* __restrict__ masks_out,
    float* __restrict__ bias1_out)
{
    __shared__ unsigned short sja[512 * 20];   // 20 KB  stored neighbor ids
    __shared__ unsigned short ska[512 * 20];   // 20 KB  stored keys (hi16)
    __shared__ float ss[512];
    __shared__ float sw8[512];
    __shared__ float smask[512];
    __shared__ float xnl[512];
    __shared__ float pl[1024];
    __shared__ float sxv[64], sq[64], sres[64], syy[64];
    __shared__ float redv[8];
    __shared__ int   redi[8];
    __shared__ float redf[8];
    __shared__ float redf2[8];
    __shared__ int mlist[12];
    __shared__ int nmin[12];
    __shared__ int s_mcnt, s_need;

    int bq = blockIdx.x;
    int row = src_row(bq);
    int tid = threadIdx.x;
    int w = tid >> 6, l = tid & 63;
    const float* Xb = x + (size_t)row * 32768;

    {   // stage idxA/keyA rows, coalesced u32 (independent of everything below)
        const unsigned* gja = (const unsigned*)(idxA + (size_t)row * 10240);
        const unsigned* gka = (const unsigned*)(keyA + (size_t)row * 10240);
        unsigned* dja = (unsigned*)sja;
        unsigned* dka = (unsigned*)ska;
        #pragma unroll
        for (int t = 0; t < 5; ++t) dja[t * 1024 + tid] = gja[t * 1024 + tid];
        #pragma unroll
        for (int t = 0; t < 5; ++t) dka[t * 1024 + tid] = gka[t * 1024 + tid];
    }
    if (tid < 512) { xnl[tid] = xn[row * 512 + tid]; smask[tid] = 1.0f; }
    if (tid < 64) sxv[tid] = x0vec[bq * 64 + tid];
    __syncthreads();
    {   // sq = w_reduce @ x0vec : 16 threads per output
        int o = tid >> 4, c0 = (tid & 15) * 4;
        const float* wr = w_reduce + o * 64 + c0;
        pl[tid] = wr[0]*sxv[c0] + wr[1]*sxv[c0+1] + wr[2]*sxv[c0+2] + wr[3]*sxv[c0+3];
    }
    __syncthreads();
    if (tid < 64) {
        float a = 0.f;
        #pragma unroll
        for (int s = 0; s < 16; ++s) a += pl[tid * 16 + s];
        sq[tid] = a;
    }
    __syncthreads();
    {   // ss[i] = 0.125 * sum_c sq[c]*X[c][i] : 2 threads per point
        int i = tid >> 1, h = tid & 1;
        float a = 0.f;
        #pragma unroll
        for (int k = 0; k < 32; ++k) {
            int c = h * 32 + k;
            a += sq[c] * Xb[c * 512 + i];
        }
        a += __shfl_xor(a, 1);
        if (h == 0) ss[i] = a * 0.125f;
    }
    __syncthreads();
    if (tid < 512) {   // fk = ss + 8-neighbor gather (neighbors = first 8 of stored row)
        float a = ss[tid];
        const unsigned short* ip = &sja[tid * 20];
        #pragma unroll
        for (int q = 0; q < 8; ++q) a += ss[ip[q]];
        sw8[tid] = a;
    }
    __syncthreads();
    {   // argmax, first-occurrence tie-break
        float bv = -3.4e38f; int bi = 0x7fffffff;
        if (tid < 512) { bv = sw8[tid]; bi = tid; }
        #pragma unroll
        for (int off = 32; off >= 1; off >>= 1) {
            float ov = __shfl_down(bv, off);
            int oi = __shfl_down(bi, off);
            if (ov > bv || (ov == bv && oi < bi)) { bv = ov; bi = oi; }
        }
        if (l == 0 && w < 8) { redv[w] = bv; redi[w] = bi; }
    }
    __syncthreads();
    if (tid == 0) {
        float Bv = redv[0]; int Bi = redi[0];
        for (int ww = 1; ww < 8; ++ww)
            if (redv[ww] > Bv || (redv[ww] == Bv && redi[ww] < Bi)) { Bv = redv[ww]; Bi = redi[ww]; }
        smask[Bi] = 0.f;
        const unsigned short* ip = &sja[Bi * 20];
        int c[9];
        c[0] = Bi;
        for (int q = 0; q < 8; ++q) { int j = ip[q]; smask[j] = 0.f; c[q + 1] = j; }
        for (int i2 = 1; i2 < 9; ++i2) {            // insertion sort asc
            int v = c[i2]; int j2 = i2 - 1;
            while (j2 >= 0 && c[j2] > v) { c[j2 + 1] = c[j2]; --j2; }
            c[j2 + 1] = v;
        }
        int mc = 0, prev = -1;
        for (int i2 = 0; i2 < 9; ++i2)
            if (c[i2] != prev) { mlist[mc++] = c[i2]; prev = c[i2]; }
        s_mcnt = mc;
        s_need = 10 - mc;
    }
    __syncthreads();
    int mcreg = s_mcnt, need = s_need;
    float sval = -3.4e38f;
    if (tid < 512) {
        masks_out[bq * 512 + tid] = smask[tid];
        sval = ss[tid] - (1.f - smask[tid]) * 1e8f;
    }
    {   // softmax max (wave shuffle + 8 partials)
        float m = sval;
        #pragma unroll
        for (int off = 32; off >= 1; off >>= 1) m = fmaxf(m, __shfl_down(m, off));
        if (l == 0 && w < 8) redf[w] = m;
    }
    __syncthreads();
    float mx = fmaxf(fmaxf(fmaxf(redf[0], redf[1]), fmaxf(redf[2], redf[3])),
                     fmaxf(fmaxf(redf[4], redf[5]), fmaxf(redf[6], redf[7])));
    float ev = 0.f;
    if (tid < 512) ev = expf(sval - mx);
    {   // softmax sum
        float s = ev;
        #pragma unroll
        for (int off = 32; off >= 1; off >>= 1) s += __shfl_down(s, off);
        if (l == 0 && w < 8) redf2[w] = s;
    }
    __syncthreads();
    {
        float sum = ((redf2[0] + redf2[1]) + (redf2[2] + redf2[3])) +
                    ((redf2[4] + redf2[5]) + (redf2[6] + redf2[7]));
        float inv = 1.f / sum;
        if (tid < 512) sw8[tid] = ev * inv;
    }
    __syncthreads();
    {   // attention pool: res[c] = sum_i sm[i]*X[c][i] ; 16 threads per channel, float4
        int c = tid >> 4, sub = tid & 15;
        const float4* xr = (const float4*)(Xb + c * 512 + sub * 32);
        const float4* wr = (const float4*)(&sw8[sub * 32]);
        float a = 0.f;
        #pragma unroll
        for (int k = 0; k < 8; ++k) {
            float4 xv = xr[k], wv = wr[k];
            a += xv.x * wv.x + xv.y * wv.y + xv.z * wv.z + xv.w * wv.w;
        }
        pl[tid] = a;
    }
    __syncthreads();
    if (tid < 64) {
        float a = 0.f;
        #pragma unroll
        for (int s = 0; s < 16; ++s) a += pl[tid * 16 + s];
        sres[tid] = a;
    }
    __syncthreads();
    {   // conv_erase partials
        int o = tid >> 4, c0 = (tid & 15) * 4;
        const float* wr = w_e + o * 64 + c0;
        pl[tid] = wr[0]*sres[c0] + wr[1]*sres[c0+1] + wr[2]*sres[c0+2] + wr[3]*sres[c0+3];
    }
    __syncthreads();
    if (tid < 64) {
        float a = b_e[tid];
        #pragma unroll
        for (int s = 0; s < 16; ++s) a += pl[tid * 16 + s];
        float sc2 = g_e[tid] / sqrtf(v_e[tid] + EPS);
        syy[tid] = (a - m_e[tid]) * sc2 + be_e[tid];
    }
    __syncthreads();
    {   // bias1 partials: w1[:,64:128] @ syy
        int o = tid >> 4, c0 = (tid & 15) * 4;
        const float* wr = w1 + o * 128 + 64 + c0;
        pl[tid] = wr[0]*syy[c0] + wr[1]*syy[c0+1] + wr[2]*syy[c0+2] + wr[3]*syy[c0+3];
    }
    __syncthreads();
    if (tid < 64) {
        float a = 0.f;
        #pragma unroll
        for (int s = 0; s < 16; ++s) a += pl[tid * 16 + s];
        bias1_out[bq * 64 + tid] = a;
    }
    // smallest-norm unmasked points (for masked queries), asc by (xn, j)
    for (int r = 0; r < need; ++r) {
        float bv = 3.4e38f; int bi = 0x7fffffff;
        if (tid < 512) {
            bv = (smask[tid] != 0.f) ? xnl[tid] : 3.4e38f;
            bi = tid;
        }
        #pragma unroll
        for (int off = 32; off >= 1; off >>= 1) {
            float ov = __shfl_down(bv, off);
            int oi = __shfl_down(bi, off);
            if (ov < bv || (ov == bv && oi < bi)) { bv = ov; bi = oi; }
        }
        if (l == 0 && w < 8) { redv[w] = bv; redi[w] = bi; }
        __syncthreads();
        if (tid == 0) {
            float Bv = redv[0]; int Bi = redi[0];
            for (int ww = 1; ww < 8; ++ww)
                if (redv[ww] < Bv || (redv[ww] == Bv && redi[ww] < Bi)) { Bv = redv[ww]; Bi = redi[ww]; }
            nmin[r] = Bi;
            xnl[Bi] = 3.4e38f;
        }
        __syncthreads();
    }
    // analytic masked-kNN: 1 query per thread, all-LDS merge
    if (tid < 512) {
        int i = tid;
        unsigned short tmp[10];
        if (smask[i] == 0.f) {
            int t2 = 0;
            for (int k2 = 0; k2 < mcreg; ++k2) tmp[t2++] = (unsigned short)mlist[k2];
            for (int r = 0; t2 < 10; ++r) tmp[t2++] = (unsigned short)nmin[r];
        } else {
            const unsigned short* ja = &sja[i * 20];
            const unsigned short* ka = &ska[i * 20];
            int pa = 0, pb = 0;
            for (int t2 = 0; t2 < 10; ++t2) {
                while (smask[ja[pa]] == 0.f) ++pa;   // skip now-masked stored entries
                unsigned kva = ka[pa];
                int jva = ja[pa];
                bool takeA = (pb >= mcreg) || (kva > 0x8000u) ||
                             (kva == 0x8000u && jva < mlist[pb]);
                if (takeA) { tmp[t2] = (unsigned short)jva; ++pa; }
                else       { tmp[t2] = (unsigned short)mlist[pb]; ++pb; }
            }
        }
        unsigned* op = (unsigned*)(idxB + (size_t)bq * 5120 + (size_t)i * 10);
        #pragma unroll
        for (int k2 = 0; k2 < 5; ++k2)
            op[k2] = (unsigned)tmp[2 * k2] | ((unsigned)tmp[2 * k2 + 1] << 16);
    }
}

// ---------------- fused branch: grid (96,8); idx u16, reg-staged (T14) ----
template<int ACC>
__global__ void __attribute__((amdgpu_flat_work_group_size(256, 256), amdgpu_waves_per_eu(2, 4)))
fused_branch_kernel(
    const _Float16* __restrict__ H, const _Float16* __restrict__ L,
    const _Float16* __restrict__ WH, const _Float16* __restrict__ WL,
    const unsigned short* __restrict__ idx, int istride,
    const float* __restrict__ masks, int remap,
    const float* __restrict__ bias,
    const float* __restrict__ g, const float* __restrict__ bb,
    const float* __restrict__ mm, const float* __restrict__ vv,
    float* __restrict__ out_p, float* __restrict__ vec_out)
{
    __shared__ float ldsA[8 * 512];
    __shared__ float ldsB[8 * 512];
    __shared__ unsigned short ldsIdx[512 * 10];
    __shared__ float smask[512];
    int bq = blockIdx.x, ob = blockIdx.y * 8;
    int row = remap ? src_row(bq) : bq;
    bool use_mask = (masks != nullptr);
    int tid = threadIdx.x, w = tid >> 6, l = tid & 63;
    int lane16 = l & 15, quad = l >> 4;
    const size_t base = (size_t)row * 32768;
    // issue idx loads into registers early; LDS write deferred past the MFMA phase
    unsigned idreg[10];
    if (istride == 10) {
        const unsigned* gp = (const unsigned*)idx + (size_t)bq * 2560;
        #pragma unroll
        for (int k = 0; k < 10; ++k) idreg[k] = gp[tid + k * 256];
    } else {   // stride-20 rows: dense dest d -> row i = d/5, word r = d%5 -> src i*10 + r
        const unsigned* gp = (const unsigned*)idx + (size_t)bq * 5120;
        #pragma unroll
        for (int k = 0; k < 10; ++k) {
            int d = tid + k * 256;
            int i = d / 5, r = d - i * 5;
            idreg[k] = gp[i * 10 + r];
        }
    }
    if (use_mask) {   // uniform branch: barrier legal
        smask[tid] = masks[bq * 512 + tid];
        smask[tid + 256] = masks[bq * 512 + tid + 256];
        __syncthreads();
    }
    {
        int wrow = (lane16 < 8) ? (ob + lane16) : (64 + ob + (lane16 - 8));
        size_t woff = (size_t)wrow * 64 + quad * 8;
        half8 Ah0 = *(const half8*)(WH + woff);
        half8 Ah1 = *(const half8*)(WH + woff + 32);
        half8 Al0 = *(const half8*)(WL + woff);
        half8 Al1 = *(const half8*)(WL + woff + 32);
        float* dst = (quad < 2) ? (ldsA + (quad * 4) * 512) : (ldsB + ((quad - 2) * 4) * 512);
        for (int k = 0; k < 8; ++k) {
            int it = w * 8 + k;
            size_t off = base + (((size_t)(it >> 2) * 8 + quad) * 64 + (it & 3) * 16 + lane16) * 8;
            half8 Xh0 = *(const half8*)(H + off);
            half8 Xh1 = *(const half8*)(H + off + 2048);
            half8 Xl0 = *(const half8*)(L + off);
            half8 Xl1 = *(const half8*)(L + off + 2048);
            if (use_mask) {
                float m = smask[it * 16 + lane16];
                if (m == 0.f) {
                    half8 z = {};
                    Xh0 = z; Xh1 = z; Xl0 = z; Xl1 = z;
                }
            }
            f32x4 acc = {0.f, 0.f, 0.f, 0.f};
            acc = __builtin_amdgcn_mfma_f32_16x16x32_f16(Ah0, Xh0, acc, 0, 0, 0);
            acc = __builtin_amdgcn_mfma_f32_16x16x32_f16(Ah1, Xh1, acc, 0, 0, 0);
            acc = __builtin_amdgcn_mfma_f32_16x16x32_f16(Ah0, Xl0, acc, 0, 0, 0);
            acc = __builtin_amdgcn_mfma_f32_16x16x32_f16(Ah1, Xl1, acc, 0, 0, 0);
            acc = __builtin_amdgcn_mfma_f32_16x16x32_f16(Al0, Xh0, acc, 0, 0, 0);
            acc = __builtin_amdgcn_mfma_f32_16x16x32_f16(Al1, Xh1, acc, 0, 0, 0);
            #pragma unroll
            for (int r = 0; r < 4; ++r)
                dst[r * 512 + it * 16 + lane16] = acc[r];
        }
    }
    __syncthreads();
    {   // write idx regs to LDS (dense u32)
        unsigned* dp = (unsigned*)ldsIdx;
        #pragma unroll
        for (int k = 0; k < 10; ++k) dp[tid + k * 256] = idreg[k];
    }
    __syncthreads();
    float ssr[2], str[2];
    #pragma unroll
    for (int oo = 0; oo < 2; ++oo) {
        int o = ob + w * 2 + oo;
        float sc = g[o] / sqrtf(vv[o] + EPS);
        ssr[oo] = sc;
        str[oo] = bb[o] - mm[o] * sc + bias[bq * 64 + o] * sc;
    }
    float omax[2], osum[2];
    #pragma unroll
    for (int oo = 0; oo < 2; ++oo) { omax[oo] = -3.4e38f; osum[oo] = 0.f; }
    const float* Aw = ldsA + (w * 2) * 512;
    const float* Bw = ldsB + (w * 2) * 512;
    for (int s = 0; s < 8; ++s) {
        int i = l + 64 * s;
        int idr[10];
        const unsigned short* ip = &ldsIdx[i * 10];
        #pragma unroll
        for (int q = 0; q < 10; ++q) idr[q] = ip[q];
        #pragma unroll
        for (int oo = 0; oo < 2; ++oo) {
            const float* Ao = Aw + oo * 512;
            float mx = Ao[idr[0]];
            #pragma unroll
            for (int q = 1; q < 10; ++q) mx = fmaxf(mx, Ao[idr[q]]);
            float val = (mx + Bw[oo * 512 + i]) * ssr[oo] + str[oo];
            float y = val > 0.f ? val : 0.2f * val;
            omax[oo] = fmaxf(omax[oo], y);
            osum[oo] += y;
        }
    }
    #pragma unroll
    for (int oo = 0; oo < 2; ++oo) {
        float M = omax[oo], S = osum[oo];
        #pragma unroll
        for (int off = 32; off >= 1; off >>= 1) {
            M = fmaxf(M, __shfl_down(M, off));
            S += __shfl_down(S, off);
        }
        if (l == 0) {
            int o = ob + w * 2 + oo;
            float* po = out_p + bq * 128;
            if (ACC) {
                po[o] += M;
                po[64 + o] += S * (1.f / 512.f);
            } else {
                po[o] = M;
                po[64 + o] = S * (1.f / 512.f);
                vec_out[bq * 64 + o] = M;
            }
        }
    }
}

extern "C" void kernel_launch(void* const* d_in, const int* in_sizes, int n_in,
                              void* d_out, int out_size, void* d_ws, size_t ws_size,
                              hipStream_t stream)
{
    const float* x        = (const float*)d_in[0];
    const float* w_reduce = (const float*)d_in[1];
    const float* w_erase  = (const float*)d_in[2];
    const float* b_erase  = (const float*)d_in[3];
    const float* g_erase  = (const float*)d_in[4];
    const float* be_erase = (const float*)d_in[5];
    const float* m_erase  = (const float*)d_in[6];
    const float* v_erase  = (const float*)d_in[7];
    const float* w0 = (const float*)d_in[8];
    const float* g0 = (const float*)d_in[9];
    const float* b0 = (const float*)d_in[10];
    const float* m0 = (const float*)d_in[11];
    const float* v0 = (const float*)d_in[12];
    const float* w1 = (const float*)d_in[13];
    const float* g1 = (const float*)d_in[14];
    const float* b1 = (const float*)d_in[15];
    const float* m1 = (const float*)d_in[16];
    const float* v1 = (const float*)d_in[17];
    float* out = (float*)d_out;
    char* ws = (char*)d_ws;

    _Float16* h0 = (_Float16*)(ws);                          // 6,291,456
    _Float16* l0 = (_Float16*)(ws + 6291456);                // 6,291,456
    unsigned short* idxA = (unsigned short*)(ws + 12582912); // 96*512*20*2 = 1,966,080
    unsigned short* keyA = (unsigned short*)(ws + 14548992); // 1,966,080
    unsigned short* idxB = (unsigned short*)(ws + 16515072); // 96*512*10*2 = 983,040
    float* xn0   = (float*)(ws + 17498112);                  // 196,608
    float* bias0 = (float*)(ws + 17694720);                  // 24,576
    float* bias1 = (float*)(ws + 17719296);                  // 24,576
    float* x0vec = (float*)(ws + 17743872);                  // 24,576
    float* masks = (float*)(ws + 17768448);                  // 196,608
    _Float16* wh0 = (_Float16*)(ws + 17965056);              // 16,384
    _Float16* wl0 = (_Float16*)(ws + 17981440);              // 16,384
    _Float16* wh1 = (_Float16*)(ws + 17997824);              // 16,384
    _Float16* wl1 = (_Float16*)(ws + 18014208);              // 16,384 (end 18,030,592)

    (void)in_sizes; (void)n_in; (void)out_size; (void)ws_size;

    // 1. prep (768) + erase0 (96)
    prep_kernel<<<864, 256, 0, stream>>>(x, h0, l0, xn0, w0, w1, wh0, wl0, wh1, wl1,
                                         w_erase, b_erase, g_erase, be_erase, m_erase, v_erase, bias0);
    // 2. kNN on x (translation-invariant), top-20 + 16-bit keys per query
    knn_kernel<<<768, 256, 0, stream>>>(h0, l0, xn0, idxA, keyA);
    // 3. branch 0 (top-10 = first 10 of stride-20 lists)
    fused_branch_kernel<0><<<dim3(96, 8), 256, 0, stream>>>(h0, l0, wh0, wl0, idxA, 20,
                                                            nullptr, 0, bias0,
                                                            g0, b0, m0, v0, out, x0vec);
    // 4. corre + erase1 + analytic masked-kNN (96 x 1024, all-LDS merge)
    derive_kernel<<<96, 1024, 0, stream>>>(x, x0vec, w_reduce, idxA, keyA, xn0,
                                           w_erase, b_erase, g_erase, be_erase, m_erase, v_erase,
                                           w1, idxB, masks, bias1);
    // 5. branch 1
    fused_branch_kernel<1><<<dim3(96, 8), 256, 0, stream>>>(h0, l0, wh1, wl1, idxB, 10,
                                                            masks, 1, bias1,
                                                            g1, b1, m1, v1, out, nullptr);
}

// Round 9
// 179.874 us; speedup vs baseline: 1.0230x; 1.0230x over previous
//
#include <hip/hip_runtime.h>
#include <math.h>

#define EPS 1e-5f

typedef _Float16 half8 __attribute__((ext_vector_type(8)));
typedef float f32x4 __attribute__((ext_vector_type(4)));

// H/L global layout per row: [tile(8)][chunk(8)][col(64)] x 8 halves (16B units).

// bq in [0,96): b = bq/12, t = bq%12; x1seq row = b*12 + min(t+1, 11)
__device__ __forceinline__ int src_row(int bq) {
    int b = bq / 12, t = bq - b * 12;
    int t2 = (t + 1 < 12) ? (t + 1) : 11;
    return b * 12 + t2;
}

// ---------------- prep (768 blocks) + erase0 (96 blocks) fused ----------------
__global__ __launch_bounds__(256) void prep_kernel(
    const float* __restrict__ X,
    _Float16* __restrict__ H, _Float16* __restrict__ L, float* __restrict__ xn,
    const float* __restrict__ w0, const float* __restrict__ w1,
    _Float16* __restrict__ wh0, _Float16* __restrict__ wl0,
    _Float16* __restrict__ wh1, _Float16* __restrict__ wl1,
    const float* __restrict__ w_e, const float* __restrict__ b_e,
    const float* __restrict__ g_e, const float* __restrict__ be_e,
    const float* __restrict__ m_e, const float* __restrict__ v_e,
    float* __restrict__ bias0)
{
    __shared__ float lds[64 * 65];
    __shared__ float xnp[4 * 64];
    __shared__ float part[256];
    __shared__ float res[64];
    __shared__ float sy[64];
    int raw = blockIdx.x;
    int tid = threadIdx.x;
    if (raw >= 768) {
        int bq = raw - 768;
        int c = tid >> 2, p = tid & 3;
        const float* xb = X + (size_t)bq * 32768 + c * 512 + p * 128;
        float acc = 0.f;
        for (int ii = 0; ii < 128; ii += 4) {
            float4 v = *(const float4*)(xb + ii);
            acc += v.x + v.y + v.z + v.w;
        }
        part[tid] = acc;
        __syncthreads();
        if (p == 0) res[c] = (part[tid] + part[tid+1] + part[tid+2] + part[tid+3]) * (1.f/512.f);
        __syncthreads();
        if (tid < 64) {
            float a = b_e[tid];
            for (int cc = 0; cc < 64; ++cc) a += w_e[tid*64+cc] * res[cc];
            float s = g_e[tid] / sqrtf(v_e[tid] + EPS);
            sy[tid] = (a - m_e[tid]) * s + be_e[tid];
        }
        __syncthreads();
        if (tid < 64) {
            float a = 0.f;
            for (int cc = 0; cc < 64; ++cc) a += w0[tid * 128 + 64 + cc] * sy[cc];
            bias0[bq * 64 + tid] = a;
        }
        return;
    }
    int bq = raw % 96;
    int ct = raw / 96;
    const float* Xb = X + (size_t)bq * 32768 + ct * 64;
    for (int p = 0; p < 16; ++p) {
        int t = p * 256 + tid;
        int c = t >> 6, col = t & 63;
        lds[c * 65 + col] = Xb[c * 512 + col];
    }
    __syncthreads();
    int col = tid & 63, g = tid >> 6;
    half8 hv[2], lv[2];
    float s = 0.f;
    #pragma unroll
    for (int k = 0; k < 16; ++k) {
        int c = g * 16 + k;
        float v = lds[c * 65 + col];
        _Float16 h = (_Float16)v;
        _Float16 lo = (_Float16)(v - (float)h);
        hv[k >> 3][k & 7] = h;
        lv[k >> 3][k & 7] = lo;
        s += v * v;
    }
    size_t obase = (size_t)bq * 32768 + ((size_t)(ct * 8 + 2 * g) * 64 + col) * 8;
    *(half8*)(H + obase) = hv[0];
    *(half8*)(H + obase + 512) = hv[1];
    *(half8*)(L + obase) = lv[0];
    *(half8*)(L + obase + 512) = lv[1];
    xnp[g * 64 + col] = s;
    __syncthreads();
    if (tid < 64)
        xn[bq * 512 + ct * 64 + tid] =
            xnp[tid] + xnp[64 + tid] + xnp[128 + tid] + xnp[192 + tid];
    if (raw < 2) {
        const float* W = raw ? w1 : w0;
        _Float16* WH = raw ? wh1 : wh0;
        _Float16* WL = raw ? wl1 : wl0;
        for (int t = tid; t < 8192; t += 256) {
            int o = t >> 6, c = t & 63;
            float v = (o < 64) ? W[o * 128 + c]
                               : (W[(o - 64) * 128 + 64 + c] - W[(o - 64) * 128 + c]);
            _Float16 h = (_Float16)v;
            WH[t] = h;
            WL[t] = (_Float16)(v - (float)h);
        }
    }
}

// ---------------- kNN v9: packed key|id u32 lists, top-20/lane, unmasked only ----
// Key layout: [key25 bits 31:7][(7-jt)<<4 | (15-slot) bits 6:0].
// Higher packed word = better score; ties resolve to lower j (matches top_k).
__global__ __launch_bounds__(256, 4) void knn_kernel(
    const _Float16* __restrict__ H, const _Float16* __restrict__ L,
    const float* __restrict__ xn,
    unsigned short* __restrict__ idx_out, unsigned short* __restrict__ key_out)
{
    __shared__ float4 jbuf[2048];                      // 32 KB; final-merge scratch aliases this
    __shared__ float sxn[512];                         // staged norms (kills global load in pack chain)
    int raw = blockIdx.x;
    int bq = raw % 96;
    int itile = raw / 96;
    int tid = threadIdx.x, w = tid >> 6, l = tid & 63;
    int lane16 = l & 15, quad = l >> 4;
    const size_t base = (size_t)bq * 32768;
    const _Float16* Hb = H + base;
    const _Float16* Lb = L + base;

    int irow = itile * 64 + w * 16 + lane16;
    size_t bo = ((size_t)(itile * 8 + quad) * 64 + (w * 16 + lane16)) * 8;
    half8 Bh0 = *(const half8*)(Hb + bo);
    half8 Bh1 = *(const half8*)(Hb + bo + 2048);
    half8 Bl0 = *(const half8*)(Lb + bo);
    half8 Bl1 = *(const half8*)(Lb + bo + 2048);

    unsigned kv[20];
    #pragma unroll
    for (int qq = 0; qq < 20; ++qq) kv[qq] = 0u;

    auto casu = [](unsigned& a, unsigned& b) {
        unsigned mn = a < b ? a : b;
        unsigned mx = a < b ? b : a;
        a = mn; b = mx;
    };

    const float* xnb = xn + bq * 512;
    float4* jbH = jbuf;
    float4* jbL = jbuf + 1024;
    {   // stage tile 0 into buffer 0 + xn row
        const float4* gh = (const float4*)(Hb);
        const float4* gl = (const float4*)(Lb);
        jbH[tid] = gh[tid]; jbH[256 + tid] = gh[256 + tid];
        jbL[tid] = gl[tid]; jbL[256 + tid] = gl[256 + tid];
        sxn[tid] = xnb[tid]; sxn[256 + tid] = xnb[256 + tid];
    }
    __syncthreads();
    for (int jt = 0; jt < 8; ++jt) {
        int cur = jt & 1;
        float4 pa0, pa1, pb0, pb1;
        if (jt < 7) {                      // issue next-tile loads; hidden behind sort
            const float4* gh = (const float4*)(Hb + (jt + 1) * 4096);
            const float4* gl = (const float4*)(Lb + (jt + 1) * 4096);
            pa0 = gh[tid]; pa1 = gh[256 + tid];
            pb0 = gl[tid]; pb1 = gl[256 + tid];
        }
        const _Float16* jH = (const _Float16*)(jbH + cur * 512);
        const _Float16* jL = (const _Float16*)(jbL + cur * 512);
        unsigned scb = (unsigned)((7 - jt) << 4);      // scalar per jt
        unsigned d[16];
        #pragma unroll
        for (int g = 0; g < 4; ++g) {
            int u = quad * 64 + g * 16 + lane16;
            half8 Ah0 = *(const half8*)(jH + (size_t)u * 8);
            half8 Ah1 = *(const half8*)(jH + (size_t)u * 8 + 2048);
            half8 Al0 = *(const half8*)(jL + (size_t)u * 8);
            half8 Al1 = *(const half8*)(jL + (size_t)u * 8 + 2048);
            f32x4 acc = {0.f, 0.f, 0.f, 0.f};
            acc = __builtin_amdgcn_mfma_f32_16x16x32_f16(Ah0, Bh0, acc, 0, 0, 0);
            acc = __builtin_amdgcn_mfma_f32_16x16x32_f16(Ah1, Bh1, acc, 0, 0, 0);
            acc = __builtin_amdgcn_mfma_f32_16x16x32_f16(Al0, Bh0, acc, 0, 0, 0);
            acc = __builtin_amdgcn_mfma_f32_16x16x32_f16(Al1, Bh1, acc, 0, 0, 0);
            acc = __builtin_amdgcn_mfma_f32_16x16x32_f16(Ah0, Bl0, acc, 0, 0, 0);
            acc = __builtin_amdgcn_mfma_f32_16x16x32_f16(Ah1, Bl1, acc, 0, 0, 0);
            int jb = jt * 64 + g * 16 + quad * 4;
            float4 xn4 = *(const float4*)&sxn[jb];
            #pragma unroll
            for (int r = 0; r < 4; ++r) {
                float xnr = (r == 0 ? xn4.x : r == 1 ? xn4.y : r == 2 ? xn4.z : xn4.w);
                float sc = fmaf(2.f, acc[r], -xnr);
                int bi = __float_as_int(sc);
                unsigned u2 = (unsigned)(bi ^ ((bi >> 31) | 0x80000000));
                int slot = g * 4 + r;
                d[slot] = (u2 & 0xFFFFFF80u) | (scb | (unsigned)(15 - slot));
            }
        }
        // bitonic sort 16 ascending
        #pragma unroll
        for (int p = 1; p < 16; p <<= 1) {
            #pragma unroll
            for (int k = p; k >= 1; k >>= 1) {
                #pragma unroll
                for (int j = k & (p - 1); j + k < 16; j += 2 * k) {
                    #pragma unroll
                    for (int i = 0; i < k; ++i) {
                        if ((i + j + k < 16) &&
                            ((i + j) / (2 * p) == (i + j + k) / (2 * p)))
                            casu(d[i + j], d[i + j + k]);
                    }
                }
            }
        }
        // merge into asc top-20 list: elementwise max (valley), then bitonic cleanup
        #pragma unroll
        for (int i = 0; i < 16; ++i) {
            unsigned dv = d[15 - i];
            kv[i] = kv[i] > dv ? kv[i] : dv;
        }
        // valley(20) -> asc: merge-32 network with OOB (>=20, +inf pads) dropped
        casu(kv[0],kv[16]); casu(kv[1],kv[17]); casu(kv[2],kv[18]); casu(kv[3],kv[19]);
        casu(kv[0],kv[8]);  casu(kv[1],kv[9]);  casu(kv[2],kv[10]); casu(kv[3],kv[11]);
        casu(kv[4],kv[12]); casu(kv[5],kv[13]); casu(kv[6],kv[14]); casu(kv[7],kv[15]);
        casu(kv[0],kv[4]);  casu(kv[1],kv[5]);  casu(kv[2],kv[6]);  casu(kv[3],kv[7]);
        casu(kv[8],kv[12]); casu(kv[9],kv[13]); casu(kv[10],kv[14]); casu(kv[11],kv[15]);
        casu(kv[0],kv[2]);  casu(kv[1],kv[3]);  casu(kv[4],kv[6]);  casu(kv[5],kv[7]);
        casu(kv[8],kv[10]); casu(kv[9],kv[11]); casu(kv[12],kv[14]); casu(kv[13],kv[15]);
        casu(kv[16],kv[18]); casu(kv[17],kv[19]);
        casu(kv[0],kv[1]);  casu(kv[2],kv[3]);  casu(kv[4],kv[5]);  casu(kv[6],kv[7]);
        casu(kv[8],kv[9]);  casu(kv[10],kv[11]); casu(kv[12],kv[13]); casu(kv[14],kv[15]);
        casu(kv[16],kv[17]); casu(kv[18],kv[19]);

        if (jt < 7) {                      // write next buffer; prev readers barrier-protected
            jbH[(1 - cur) * 512 + tid] = pa0; jbH[(1 - cur) * 512 + 256 + tid] = pa1;
            jbL[(1 - cur) * 512 + tid] = pb0; jbL[(1 - cur) * 512 + 256 + tid] = pb1;
        }
        __syncthreads();
    }
    // dump per-lane lists into scratch aliased over jbuf (all jbuf reads done)
    unsigned* MVb = (unsigned*)jbuf;
    #pragma unroll
    for (int qq = 0; qq < 20; ++qq)
        MVb[w * 1344 + (lane16 * 4 + quad) * 21 + qq] = kv[qq];
    __syncthreads();
    if (quad == 0) {
        // raw packed compare is the full (key, smaller-j) order:
        //  - within a quad, low 7 bits order by j already
        //  - across quads, equal packed words differ in j only by quad*4 -> first quad wins
        const unsigned* MV = (const unsigned*)jbuf + w * 1344 + lane16 * 84;
        int p0 = 19, p1 = 19, p2 = 19, p3 = 19;
        unsigned v0 = MV[19], v1 = MV[21 + 19], v2 = MV[42 + 19], v3 = MV[63 + 19];
        unsigned short* op = idx_out + ((size_t)bq * 512 + irow) * 20;
        unsigned short* kp = key_out + ((size_t)bq * 512 + irow) * 20;
        for (int t = 0; t < 20; ++t) {
            int bc = 0; unsigned bv = v0;
            if (v1 > bv) { bv = v1; bc = 1; }
            if (v2 > bv) { bv = v2; bc = 2; }
            if (v3 > bv) { bv = v3; bc = 3; }
            int bits = (int)(bv & 127u), jtv = 7 - (bits >> 4), cod = 15 - (bits & 15);
            int j = jtv * 64 + ((cod >> 2) << 4) + bc * 4 + (cod & 3);
            op[t] = (unsigned short)j;
            kp[t] = (unsigned short)(bv >> 16);
            if (bc == 0)      { --p0; v0 = MV[p0 < 0 ? 0 : p0]; }
            else if (bc == 1) { --p1; v1 = MV[21 + (p1 < 0 ? 0 : p1)]; }
            else if (bc == 2) { --p2; v2 = MV[42 + (p2 < 0 ? 0 : p2)]; }
            else              { --p3; v3 = MV[63 + (p3 < 0 ? 0 : p3)]; }
        }
    }
}

// ---------------- derive v2 (96 blocks x 1024 threads): corre + erase1 + merge ----
// All list/merge state staged to LDS; shuffle reductions; 16 waves/block for latency hiding.
__global__ __launch_bounds__(1024) void derive_kernel(
    const float* __restrict__ x, const float* __restrict__ x0vec,
    const float* __restrict__ w_reduce,
    const unsigned short* __restrict__ idxA, const unsigned short* __restrict__ keyA,
    const float* __restrict__ xn,
    const float* __restrict__ w_e, const float* __restrict__ b_e,
    const float* __restrict__ g_e, const float* __restrict__ be_e,
    const float* __restrict__ m_e, const float* __restrict__ v_e,
    const float* __restrict__ w1,
    unsigned short* __restrict__ idxB, float* __restrict__ masks_out,
    float* __restrict__ bias1_out)
{
    __shared__ unsigned short sja[512 * 20];   // 20 KB  stored neighbor ids
    __shared__ unsigned short ska[512 * 20];   // 20 KB  stored keys (hi16)
    __shared__ float ss[512];
    __shared__ float sw8[512];
    __shared__ float smask[512];
    __shared__ float xnl[512];
    __shared__ float pl[1024];
    __shared__ float sxv[64], sq[64], sres[64], syy[64];
    __shared__ float redv[8];
    __shared__ int   redi[8];
    __shared__ float redf[8];
    __shared__ float redf2[8];
    __shared__ int mlist[12];
    __shared__ int nmin[12];
    __shared__ int s_mcnt, s_need;

    int bq = blockIdx.x;
    int row = src_row(bq);
    int tid = threadIdx.x;
    int w = tid >> 6, l = tid & 63;
    const float* Xb = x + (size_t)row * 32768;

    {   // stage idxA/keyA rows, coalesced u32 (independent of everything below)
        const unsigned* gja = (const unsigned*)(idxA + (size_t)row * 10240);
        const unsigned* gka = (const unsigned*)(keyA + (size_t)row * 10240);
        unsigned* dja = (unsigned*)sja;
        unsigned* dka = (unsigned*)ska;
        #pragma unroll
        for (int t = 0; t < 5; ++t) dja[t * 1024 + tid] = gja[t * 1024 + tid];
        #pragma unroll
        for (int t = 0; t < 5; ++t) dka[t * 1024 + tid] = gka[t * 1024 + tid];
    }
    if (tid < 512) { xnl[tid] = xn[row * 512 + tid]; smask[tid] = 1.0f; }
    if (tid < 64) sxv[tid] = x0vec[bq * 64 + tid];
    __syncthreads();
    {   // sq = w_reduce @ x0vec : 16 threads per output
        int o = tid >> 4, c0 = (tid & 15) * 4;
        const float* wr = w_reduce + o * 64 + c0;
        pl[tid] = wr[0]*sxv[c0] + wr[1]*sxv[c0+1] + wr[2]*sxv[c0+2] + wr[3]*sxv[c0+3];
    }
    __syncthreads();
    if (tid < 64) {
        float a = 0.f;
        #pragma unroll
        for (int s = 0; s < 16; ++s) a += pl[tid * 16 + s];
        sq[tid] = a;
    }
    __syncthreads();
    {   // ss[i] = 0.125 * sum_c sq[c]*X[c][i] : 2 threads per point
        int i = tid >> 1, h = tid & 1;
        float a = 0.f;
        #pragma unroll
        for (int k = 0; k < 32; ++k) {
            int c = h * 32 + k;
            a += sq[c] * Xb[c * 512 + i];
        }
        a += __shfl_xor(a, 1);
        if (h == 0) ss[i] = a * 0.125f;
    }
    __syncthreads();
    if (tid < 512) {   // fk = ss + 8-neighbor gather (neighbors = first 8 of stored row)
        float a = ss[tid];
        const unsigned short* ip = &sja[tid * 20];
        #pragma unroll
        for (int q = 0; q < 8; ++q) a += ss[ip[q]];
        sw8[tid] = a;
    }
    __syncthreads();
    {   // argmax, first-occurrence tie-break
        float bv = -3.4e38f; int bi = 0x7fffffff;
        if (tid < 512) { bv = sw8[tid]; bi = tid; }
        #pragma unroll
        for (int off = 32; off >= 1; off >>= 1) {
            float ov = __shfl_down(bv, off);
            int oi = __shfl_down(bi, off);
            if (ov > bv || (ov == bv && oi < bi)) { bv = ov; bi = oi; }
        }
        if (l == 0 && w < 8) { redv[w] = bv; redi[w] = bi; }
    }
    __syncthreads();
    if (tid == 0) {
        float Bv = redv[0]; int Bi = redi[0];
        for (int ww = 1; ww < 8; ++ww)
            if (redv[ww] > Bv || (redv[ww] == Bv && redi[ww] < Bi)) { Bv = redv[ww]; Bi = redi[ww]; }
        smask[Bi] = 0.f;
        const unsigned short* ip = &sja[Bi * 20];
        int c[9];
        c[0] = Bi;
        for (int q = 0; q < 8; ++q) { int j = ip[q]; smask[j] = 0.f; c[q + 1] = j; }
        for (int i2 = 1; i2 < 9; ++i2) {            // insertion sort asc
            int v = c[i2]; int j2 = i2 - 1;
            while (j2 >= 0 && c[j2] > v) { c[j2 + 1] = c[j2]; --j2; }
            c[j2 + 1] = v;
        }
        int mc = 0, prev = -1;
        for (int i2 = 0; i2 < 9; ++i2)
            if (c[i2] != prev) { mlist[mc++] = c[i2]; prev = c[i2]; }
        s_mcnt = mc;
        s_need = 10 - mc;
    }
    __syncthreads();
    int mcreg = s_mcnt, need = s_need;
    float sval = -3.4e38f;
    if (tid < 512) {
        masks_out[bq * 512 + tid] = smask[tid];
        sval = ss[tid] - (1.f - smask[tid]) * 1e8f;
    }
    {   // softmax max (wave shuffle + 8 partials)
        float m = sval;
        #pragma unroll
        for (int off = 32; off >= 1; off >>= 1) m = fmaxf(m, __shfl_down(m, off));
        if (l == 0 && w < 8) redf[w] = m;
    }
    __syncthreads();
    float mx = fmaxf(fmaxf(fmaxf(redf[0], redf[1]), fmaxf(redf[2], redf[3])),
                     fmaxf(fmaxf(redf[4], redf[5]), fmaxf(redf[6], redf[7])));
    float ev = 0.f;
    if (tid < 512) ev = expf(sval - mx);
    {   // softmax sum
        float s = ev;
        #pragma unroll
        for (int off = 32; off >= 1; off >>= 1) s += __shfl_down(s, off);
        if (l == 0 && w < 8) redf2[w] = s;
    }
    __syncthreads();
    {
        float sum = ((redf2[0] + redf2[1]) + (redf2[2] + redf2[3])) +
                    ((redf2[4] + redf2[5]) + (redf2[6] + redf2[7]));
        float inv = 1.f / sum;
        if (tid < 512) sw8[tid] = ev * inv;
    }
    __syncthreads();
    {   // attention pool: res[c] = sum_i sm[i]*X[c][i] ; 16 threads per channel, float4
        int c = tid >> 4, sub = tid & 15;
        const float4* xr = (const float4*)(Xb + c * 512 + sub * 32);
        const float4* wr = (const float4*)(&sw8[sub * 32]);
        float a = 0.f;
        #pragma unroll
        for (int k = 0; k < 8; ++k) {
            float4 xv = xr[k], wv = wr[k];
            a += xv.x * wv.x + xv.y * wv.y + xv.z * wv.z + xv.w * wv.w;
        }
        pl[tid] = a;
    }
    __syncthreads();
    if (tid < 64) {
        float a = 0.f;
        #pragma unroll
        for (int s = 0; s < 16; ++s) a += pl[tid * 16 + s];
        sres[tid] = a;
    }
    __syncthreads();
    {   // conv_erase partials
        int o = tid >> 4, c0 = (tid & 15) * 4;
        const float* wr = w_e + o * 64 + c0;
        pl[tid] = wr[0]*sres[c0] + wr[1]*sres[c0+1] + wr[2]*sres[c0+2] + wr[3]*sres[c0+3];
    }
    __syncthreads();
    if (tid < 64) {
        float a = b_e[tid];
        #pragma unroll
        for (int s = 0; s < 16; ++s) a += pl[tid * 16 + s];
        float sc2 = g_e[tid] / sqrtf(v_e[tid] + EPS);
        syy[tid] = (a - m_e[tid]) * sc2 + be_e[tid];
    }
    __syncthreads();
    {   // bias1 partials: w1[:,64:128] @ syy
        int o = tid >> 4, c0 = (tid & 15) * 4;
        const float* wr = w1 + o * 128 + 64 + c0;
        pl[tid] = wr[0]*syy[c0] + wr[1]*syy[c0+1] + wr[2]*syy[c0+2] + wr[3]*syy[c0+3];
    }
    __syncthreads();
    if (tid < 64) {
        float a = 0.f;
        #pragma unroll
        for (int s = 0; s < 16; ++s) a += pl[tid * 16 + s];
        bias1_out[bq * 64 + tid] = a;
    }
    // smallest-norm unmasked points (for masked queries), asc by (xn, j)
    for (int r = 0; r < need; ++r) {
        float bv = 3.4e38f; int bi = 0x7fffffff;
        if (tid < 512) {
            bv = (smask[tid] != 0.f) ? xnl[tid] : 3.4e38f;
            bi = tid;
        }
        #pragma unroll
        for (int off = 32; off >= 1; off >>= 1) {
            float ov = __shfl_down(bv, off);
            int oi = __shfl_down(bi, off);
            if (ov < bv || (ov == bv && oi < bi)) { bv = ov; bi = oi; }
        }
        if (l == 0 && w < 8) { redv[w] = bv; redi[w] = bi; }
        __syncthreads();
        if (tid == 0) {
            float Bv = redv[0]; int Bi = redi[0];
            for (int ww = 1; ww < 8; ++ww)
                if (redv[ww] < Bv || (redv[ww] == Bv && redi[ww] < Bi)) { Bv = redv[ww]; Bi = redi[ww]; }
            nmin[r] = Bi;
            xnl[Bi] = 3.4e38f;
        }
        __syncthreads();
    }
    // analytic masked-kNN: 1 query per thread, all-LDS merge
    if (tid < 512) {
        int i = tid;
        unsigned short tmp[10];
        if (smask[i] == 0.f) {
            int t2 = 0;
            for (int k2 = 0; k2 < mcreg; ++k2) tmp[t2++] = (unsigned short)mlist[k2];
            for (int r = 0; t2 < 10; ++r) tmp[t2++] = (unsigned short)nmin[r];
        } else {
            const unsigned short* ja = &sja[i * 20];
            const unsigned short* ka = &ska[i * 20];
            int pa = 0, pb = 0;
            for (int t2 = 0; t2 < 10; ++t2) {
                while (smask[ja[pa]] == 0.f) ++pa;   // skip now-masked stored entries
                unsigned kva = ka[pa];
                int jva = ja[pa];
                bool takeA = (pb >= mcreg) || (kva > 0x8000u) ||
                             (kva == 0x8000u && jva < mlist[pb]);
                if (takeA) { tmp[t2] = (unsigned short)jva; ++pa; }
                else       { tmp[t2] = (unsigned short)mlist[pb]; ++pb; }
            }
        }
        unsigned* op = (unsigned*)(idxB + (size_t)bq * 5120 + (size_t)i * 10);
        #pragma unroll
        for (int k2 = 0; k2 < 5; ++k2)
            op[k2] = (unsigned)tmp[2 * k2] | ((unsigned)tmp[2 * k2 + 1] << 16);
    }
}

// ---------------- fused branch: grid (96,8); idx u16, reg-staged (T14) ----
template<int ACC>
__global__ void __attribute__((amdgpu_flat_work_group_size(256, 256), amdgpu_waves_per_eu(2, 4)))
fused_branch_kernel(
    const _Float16* __restrict__ H, const _Float16* __restrict__ L,
    const _Float16* __restrict__ WH, const _Float16* __restrict__ WL,
    const unsigned short* __restrict__ idx, int istride,
    const float* __restrict__ masks, int remap,
    const float* __restrict__ bias,
    const float* __restrict__ g, const float* __restrict__ bb,
    const float* __restrict__ mm, const float* __restrict__ vv,
    float* __restrict__ out_p, float* __restrict__ vec_out)
{
    __shared__ float ldsA[8 * 512];
    __shared__ float ldsB[8 * 512];
    __shared__ unsigned short ldsIdx[512 * 10];
    __shared__ float smask[512];
    int bq = blockIdx.x, ob = blockIdx.y * 8;
    int row = remap ? src_row(bq) : bq;
    bool use_mask = (masks != nullptr);
    int tid = threadIdx.x, w = tid >> 6, l = tid & 63;
    int lane16 = l & 15, quad = l >> 4;
    const size_t base = (size_t)row * 32768;
    // issue idx loads into registers early; LDS write deferred past the MFMA phase
    unsigned idreg[10];
    if (istride == 10) {
        const unsigned* gp = (const unsigned*)idx + (size_t)bq * 2560;
        #pragma unroll
        for (int k = 0; k < 10; ++k) idreg[k] = gp[tid + k * 256];
    } else {   // stride-20 rows: dense dest d -> row i = d/5, word r = d%5 -> src i*10 + r
        const unsigned* gp = (const unsigned*)idx + (size_t)bq * 5120;
        #pragma unroll
        for (int k = 0; k < 10; ++k) {
            int d = tid + k * 256;
            int i = d / 5, r = d - i * 5;
            idreg[k] = gp[i * 10 + r];
        }
    }
    if (use_mask) {   // uniform branch: barrier legal
        smask[tid] = masks[bq * 512 + tid];
        smask[tid + 256] = masks[bq * 512 + tid + 256];
        __syncthreads();
    }
    {
        int wrow = (lane16 < 8) ? (ob + lane16) : (64 + ob + (lane16 - 8));
        size_t woff = (size_t)wrow * 64 + quad * 8;
        half8 Ah0 = *(const half8*)(WH + woff);
        half8 Ah1 = *(const half8*)(WH + woff + 32);
        half8 Al0 = *(const half8*)(WL + woff);
        half8 Al1 = *(const half8*)(WL + woff + 32);
        float* dst = (quad < 2) ? (ldsA + (quad * 4) * 512) : (ldsB + ((quad - 2) * 4) * 512);
        for (int k = 0; k < 8; ++k) {
            int it = w * 8 + k;
            size_t off = base + (((size_t)(it >> 2) * 8 + quad) * 64 + (it & 3) * 16 + lane16) * 8;
            half8 Xh0 = *(const half8*)(H + off);
            half8 Xh1 = *(const half8*)(H + off + 2048);
            half8 Xl0 = *(const half8*)(L + off);
            half8 Xl1 = *(const half8*)(L + off + 2048);
            if (use_mask) {
                float m = smask[it * 16 + lane16];
                if (m == 0.f) {
                    half8 z = {};
                    Xh0 = z; Xh1 = z; Xl0 = z; Xl1 = z;
                }
            }
            f32x4 acc = {0.f, 0.f, 0.f, 0.f};
            acc = __builtin_amdgcn_mfma_f32_16x16x32_f16(Ah0, Xh0, acc, 0, 0, 0);
            acc = __builtin_amdgcn_mfma_f32_16x16x32_f16(Ah1, Xh1, acc, 0, 0, 0);
            acc = __builtin_amdgcn_mfma_f32_16x16x32_f16(Ah0, Xl0, acc, 0, 0, 0);
            acc = __builtin_amdgcn_mfma_f32_16x16x32_f16(Ah1, Xl1, acc, 0, 0, 0);
            acc = __builtin_amdgcn_mfma_f32_16x16x32_f16(Al0, Xh0, acc, 0, 0, 0);
            acc = __builtin_amdgcn_mfma_f32_16x16x32_f16(Al1, Xh1, acc, 0, 0, 0);
            #pragma unroll
            for (int r = 0; r < 4; ++r)
                dst[r * 512 + it * 16 + lane16] = acc[r];
        }
    }
    __syncthreads();
    {   // write idx regs to LDS (dense u32)
        unsigned* dp = (unsigned*)ldsIdx;
        #pragma unroll
        for (int k = 0; k < 10; ++k) dp[tid + k * 256] = idreg[k];
    }
    __syncthreads();
    float ssr[2], str[2];
    #pragma unroll
    for (int oo = 0; oo < 2; ++oo) {
        int o = ob + w * 2 + oo;
        float sc = g[o] / sqrtf(vv[o] + EPS);
        ssr[oo] = sc;
        str[oo] = bb[o] - mm[o] * sc + bias[bq * 64 + o] * sc;
    }
    float omax[2], osum[2];
    #pragma unroll
    for (int oo = 0; oo < 2; ++oo) { omax[oo] = -3.4e38f; osum[oo] = 0.f; }
    const float* Aw = ldsA + (w * 2) * 512;
    const float* Bw = ldsB + (w * 2) * 512;
    for (int s = 0; s < 8; ++s) {
        int i = l + 64 * s;
        int idr[10];
        const unsigned short* ip = &ldsIdx[i * 10];
        #pragma unroll
        for (int q = 0; q < 10; ++q) idr[q] = ip[q];
        #pragma unroll
        for (int oo = 0; oo < 2; ++oo) {
            const float* Ao = Aw + oo * 512;
            float mx = Ao[idr[0]];
            #pragma unroll
            for (int q = 1; q < 10; ++q) mx = fmaxf(mx, Ao[idr[q]]);
            float val = (mx + Bw[oo * 512 + i]) * ssr[oo] + str[oo];
            float y = val > 0.f ? val : 0.2f * val;
            omax[oo] = fmaxf(omax[oo], y);
            osum[oo] += y;
        }
    }
    #pragma unroll
    for (int oo = 0; oo < 2; ++oo) {
        float M = omax[oo], S = osum[oo];
        #pragma unroll
        for (int off = 32; off >= 1; off >>= 1) {
            M = fmaxf(M, __shfl_down(M, off));
            S += __shfl_down(S, off);
        }
        if (l == 0) {
            int o = ob + w * 2 + oo;
            float* po = out_p + bq * 128;
            if (ACC) {
                po[o] += M;
                po[64 + o] += S * (1.f / 512.f);
            } else {
                po[o] = M;
                po[64 + o] = S * (1.f / 512.f);
                vec_out[bq * 64 + o] = M;
            }
        }
    }
}

extern "C" void kernel_launch(void* const* d_in, const int* in_sizes, int n_in,
                              void* d_out, int out_size, void* d_ws, size_t ws_size,
                              hipStream_t stream)
{
    const float* x        = (const float*)d_in[0];
    const float* w_reduce = (const float*)d_in[1];
    const float* w_erase  = (const float*)d_in[2];
    const float* b_erase  = (const float*)d_in[3];
    const float* g_erase  = (const float*)d_in[4];
    const float* be_erase = (const float*)d_in[5];
    const float* m_erase  = (const float*)d_in[6];
    const float* v_erase  = (const float*)d_in[7];
    const float* w0 = (const float*)d_in[8];
    const float* g0 = (const float*)d_in[9];
    const float* b0 = (const float*)d_in[10];
    const float* m0 = (const float*)d_in[11];
    const float* v0 = (const float*)d_in[12];
    const float* w1 = (const float*)d_in[13];
    const float* g1 = (const float*)d_in[14];
    const float* b1 = (const float*)d_in[15];
    const float* m1 = (const float*)d_in[16];
    const float* v1 = (const float*)d_in[17];
    float* out = (float*)d_out;
    char* ws = (char*)d_ws;

    _Float16* h0 = (_Float16*)(ws);                          // 6,291,456
    _Float16* l0 = (_Float16*)(ws + 6291456);                // 6,291,456
    unsigned short* idxA = (unsigned short*)(ws + 12582912); // 96*512*20*2 = 1,966,080
    unsigned short* keyA = (unsigned short*)(ws + 14548992); // 1,966,080
    unsigned short* idxB = (unsigned short*)(ws + 16515072); // 96*512*10*2 = 983,040
    float* xn0   = (float*)(ws + 17498112);                  // 196,608
    float* bias0 = (float*)(ws + 17694720);                  // 24,576
    float* bias1 = (float*)(ws + 17719296);                  // 24,576
    float* x0vec = (float*)(ws + 17743872);                  // 24,576
    float* masks = (float*)(ws + 17768448);                  // 196,608
    _Float16* wh0 = (_Float16*)(ws + 17965056);              // 16,384
    _Float16* wl0 = (_Float16*)(ws + 17981440);              // 16,384
    _Float16* wh1 = (_Float16*)(ws + 17997824);              // 16,384
    _Float16* wl1 = (_Float16*)(ws + 18014208);              // 16,384 (end 18,030,592)

    (void)in_sizes; (void)n_in; (void)out_size; (void)ws_size;

    // 1. prep (768) + erase0 (96)
    prep_kernel<<<864, 256, 0, stream>>>(x, h0, l0, xn0, w0, w1, wh0, wl0, wh1, wl1,
                                         w_erase, b_erase, g_erase, be_erase, m_erase, v_erase, bias0);
    // 2. kNN on x (translation-invariant), top-20 + 16-bit keys per query
    knn_kernel<<<768, 256, 0, stream>>>(h0, l0, xn0, idxA, keyA);
    // 3. branch 0 (top-10 = first 10 of stride-20 lists)
    fused_branch_kernel<0><<<dim3(96, 8), 256, 0, stream>>>(h0, l0, wh0, wl0, idxA, 20,
                                                            nullptr, 0, bias0,
                                                            g0, b0, m0, v0, out, x0vec);
    // 4. corre + erase1 + analytic masked-kNN (96 x 1024, all-LDS merge)
    derive_kernel<<<96, 1024, 0, stream>>>(x, x0vec, w_reduce, idxA, keyA, xn0,
                                           w_erase, b_erase, g_erase, be_erase, m_erase, v_erase,
                                           w1, idxB, masks, bias1);
    // 5. branch 1
    fused_branch_kernel<1><<<dim3(96, 8), 256, 0, stream>>>(h0, l0, wh1, wl1, idxB, 10,
                                                            masks, 1, bias1,
                                                            g1, b1, m1, v1, out, nullptr);
}